// Round 1
// 943.767 us; speedup vs baseline: 1.0282x; 1.0282x over previous
//
#include <hip/hip_runtime.h>
#include <math.h>

// BWNet scan v2: latency-optimized persistent kernel.
// Sync redesign: every cross-block datum is a 64-bit (tag<<32 | value) word
// written with relaxed agent-scope atomic stores and polled with relaxed
// agent-scope atomic loads. Data IS the barrier: no RMW counter contention,
// no acquire/cache-invalidate, and only TWO exchanges per step:
//   exchange 1: ri0 (256 tagged floats, 8 per block)
//   exchange 2: per-block sweep partials (sum/max/idx) + the local-argmax
//               key column (shipped so nobody re-gathers keys[:,pick])
// All other state (ar, mask, sel, done, q, h) is replicated per block and
// updated redundantly & deterministically -> identical across blocks.
// Blocks 32..255 zero unit_logits rows [steps..8192) with nontemporal stores.

typedef float v4f __attribute__((ext_vector_type(4)));
typedef unsigned long long ull;

#define N_ENT 8192
#define EMB   256
#define KD    32
#define ARD   1024
#define UT    233
#define NSCAN 32
#define NZERO 224
#define NBLK  256

// workspace float-index offsets
#define WS_KEYS 0         // 32*8192 floats, k-major: keys[k*8192+j]
#define WS_C0   262144    // 256: b_a0 + relu(W_fe@um + b_fe)
#define WS_PAIR 262400    // tagged-pair region (8B aligned: byte 1049600)
// pair (ull) indices within pair region
#define PR_RI0  0         // 256 pairs: ri0[j], written by block j>>3
#define PR_PART 256       // 32 blocks * 40 pairs: [0]=psum [1]=pmax [2]=pidx [3..34]=cand
#define NPAIRS  (256 + 32 * 40)

struct Params {
  const float *um, *emask, *enc, *arin, *W_fe, *b_fe, *W_k, *b_k,
              *W_a0, *b_a0, *W_a1, *b_a1, *W_f, *b_f, *W_i0, *b_i0,
              *W_i1, *b_i1, *W_o, *b_o, *ln_g, *ln_b, *W_a3, *b_a3;
  const int* ct;
  float* out;
  float* wsf;
  int*   wsi;
};

__device__ __forceinline__ ull ld_pair(ull* p_) {
  return __hip_atomic_load(p_, __ATOMIC_RELAXED, __HIP_MEMORY_SCOPE_AGENT);
}
__device__ __forceinline__ void st_pair(ull* p_, ull v) {
  __hip_atomic_store(p_, v, __ATOMIC_RELAXED, __HIP_MEMORY_SCOPE_AGENT);
}
__device__ __forceinline__ ull packf(float v, unsigned tag) {
  return ((ull)tag << 32) | (ull)__float_as_uint(v);
}
__device__ __forceinline__ ull packi(int v, unsigned tag) {
  return ((ull)tag << 32) | (ull)(unsigned)v;
}
__device__ __forceinline__ unsigned ptag(ull u) { return (unsigned)(u >> 32); }
__device__ __forceinline__ float pvalf(ull u) { return __uint_as_float((unsigned)u); }

// ---------------- init: keys GEMM, func_embed, zero tag pairs ----------------
__global__ __launch_bounds__(256) void k_init(Params p) {
  __shared__ float enc_s[32 * 260];  // 32 rows x 256, pad 260 vs bank conflicts
  __shared__ float um_s[UT];
  const int tid = threadIdx.x, bid = blockIdx.x;
  float* keys = p.wsf + WS_KEYS;

  if (bid == 0 && tid < UT) um_s[tid] = p.um[tid];
  if (bid == 3) {  // zero all tag pairs (tag 0 matches no step tag 1..66)
    ull* pr = (ull*)(p.wsf + WS_PAIR);
    for (int i = tid; i < NPAIRS; i += 256) pr[i] = 0ull;
  }

  // stage 32 entity rows (this block's columns j0..j0+31)
  const int j0 = bid * 32;
  #pragma unroll
  for (int i = 0; i < 8; ++i) {
    int idx = i * 256 + tid;           // float4 units, 0..2047
    int row = idx >> 6, c4 = idx & 63;
    v4f v = *(const v4f*)(p.enc + (size_t)(j0 + row) * EMB + c4 * 4);
    *(v4f*)&enc_s[row * 260 + c4 * 4] = v;
  }
  __syncthreads();
  {
    const int jl = tid >> 3, kg = tid & 7;  // 32 j x 8 k-groups
    float acc[4];
    #pragma unroll
    for (int kk = 0; kk < 4; ++kk) acc[kk] = p.b_k[kg * 4 + kk];
    for (int e4 = 0; e4 < 64; ++e4) {
      v4f x = *(const v4f*)&enc_s[jl * 260 + e4 * 4];
      #pragma unroll
      for (int kk = 0; kk < 4; ++kk) {
        v4f w = *(const v4f*)(p.W_k + (size_t)(kg * 4 + kk) * EMB + e4 * 4);
        acc[kk] += x.x * w.x + x.y * w.y + x.z * w.z + x.w * w.w;
      }
    }
    const int j = j0 + jl;
    #pragma unroll
    for (int kk = 0; kk < 4; ++kk) keys[(size_t)(kg * 4 + kk) * N_ENT + j] = acc[kk];
  }
  if (bid == 0) {  // c0 = b_a0 + relu(W_fe @ um + b_fe)
    float a = p.b_fe[tid];
    const float* wr = p.W_fe + (size_t)tid * UT;
    for (int u = 0; u < UT; ++u) a += wr[u] * um_s[u];
    p.wsf[WS_C0 + tid] = fmaxf(a, 0.f) + p.b_a0[tid];
  }
}

// ---------------- main: scan (blocks 0..31) + output zeroing (32..255) ----------------
__global__ __launch_bounds__(256, 1) void k_scan(Params p) {
  const int tid = threadIdx.x, bid = blockIdx.x;
  int ctv = p.ct[0];
  const int steps = ctv < 0 ? 0 : (ctv > 64 ? 64 : ctv);
  const size_t NN = (size_t)N_ENT * N_ENT;

  if (bid >= NSCAN) {  // -------- zero role --------
    v4f z = (v4f){0.f, 0.f, 0.f, 0.f};
    v4f* o4 = (v4f*)p.out;
    const size_t tot = NN / 4;
    for (size_t i = (size_t)steps * (N_ENT / 4) + (size_t)(bid - NSCAN) * 256 + tid;
         i < tot; i += (size_t)NZERO * 256)
      __builtin_nontemporal_store(z, o4 + i);
    return;
  }

  // -------- scan role --------
  // ar padded [32][36] so the produce-GEMV's ds_read_b128 is only 4-way banked
  __shared__ float ar_s[32 * 36];
  __shared__ float cand_s[32 * 32];      // staged candidate key columns
  __shared__ float ri0_s[8 * 33];        // relu(i0), padded
  __shared__ unsigned maskb[256], selb[256];  // 8192-entity bitmasks
  __shared__ float x_i1[32], q_s[32], h_s[32], qnf[32];
  __shared__ float garr[128], fog[32], rem[32], og[32], cent[32];
  __shared__ float b_a1s[32], gb_s[128], lng_s[32], lnb_s[32], c0own[8];
  __shared__ float psums[32], pmaxs[32];
  __shared__ int   pidxs[32];
  __shared__ float reds[4], rmaxs[4];
  __shared__ int   ridxs[4];
  __shared__ float ssum_s;
  __shared__ int   pickloc_s, hit_s, upd_s, actvalid_s, done_s;

  ull* ri0p  = (ull*)(p.wsf + WS_PAIR) + PR_RI0;
  ull* partp = (ull*)(p.wsf + WS_PAIR) + PR_PART;
  const float* keys = p.wsf + WS_KEYS;

  // ---- preamble: replicated state + weights into LDS / registers ----
  for (int i = tid; i < ARD; i += 256) ar_s[(i >> 5) * 36 + (i & 31)] = p.arin[i];
  {
    unsigned mb = 0u;
    const float* em = p.emask + (size_t)tid * 32;
    #pragma unroll
    for (int j = 0; j < 32; ++j) mb |= (em[j] != 0.f) ? (1u << j) : 0u;
    maskb[tid] = mb; selb[tid] = 0u;
  }
  if (tid < 32) {
    b_a1s[tid] = p.b_a1[tid];
    lng_s[tid] = p.ln_g[tid]; lnb_s[tid] = p.ln_b[tid];
    q_s[tid] = 0.f; h_s[tid] = 0.f; qnf[tid] = 0.f; x_i1[tid] = 0.f;
  }
  if (tid < 128) {
    const int g = tid >> 5, r = tid & 31;
    const float* bg = (g == 0) ? p.b_f : (g == 1) ? p.b_i0 : (g == 2) ? p.b_i1 : p.b_o;
    gb_s[tid] = bg[r];
  }
  if (tid < 8) c0own[tid] = p.wsf[WS_C0 + bid * 8 + tid];
  if (tid == 0) done_s = 0;

  v4f w0[8];  // W_a0 rows [8b,8b+8): thread = (row tid>>5, cols (tid&31)*32..+32)
  { const float* s = p.W_a0 + (size_t)(bid * 8 + (tid >> 5)) * ARD + (tid & 31) * 32;
    #pragma unroll
    for (int i = 0; i < 8; ++i) w0[i] = ((const v4f*)s)[i]; }
  v4f w1[8];  // W_a1: thread = (row tid>>3, cols (tid&7)*32..+32)
  { const float* s = p.W_a1 + (size_t)(tid >> 3) * EMB + (tid & 7) * 32;
    #pragma unroll
    for (int i = 0; i < 8; ++i) w1[i] = ((const v4f*)s)[i]; }
  v4f wg[8];  // LSTM gates: 128 rows x 2 halves
  { const int rowg = tid >> 1, g = rowg >> 5, r = rowg & 31, half = tid & 1;
    const float* W = (g == 0) ? p.W_f : (g == 1) ? p.W_i0 : (g == 2) ? p.W_i1 : p.W_o;
    const float* s = W + r * 64 + half * 32;
    #pragma unroll
    for (int i = 0; i < 8; ++i) wg[i] = ((const v4f*)s)[i]; }
  float kc[32];  // this thread's key column, register-resident for all 64 steps
  { const int gcol = bid * 256 + tid;
    #pragma unroll
    for (int k = 0; k < 32; ++k) kc[k] = keys[(size_t)k * N_ENT + gcol]; }
  __syncthreads();

  // produce ri0 for a given tag from LDS ar (8 rows owned by this block)
  auto produce = [&](unsigned tag) {
    const int seg = tid & 31, rl = tid >> 5;
    const float* a = &ar_s[seg * 36];
    float pa = 0.f;
    #pragma unroll
    for (int i = 0; i < 8; ++i) {
      v4f av = *(const v4f*)(a + 4 * i);
      pa += w0[i].x * av.x + w0[i].y * av.y + w0[i].z * av.z + w0[i].w * av.w;
    }
    #pragma unroll
    for (int m = 16; m; m >>= 1) pa += __shfl_xor(pa, m);
    if (seg == 0)
      st_pair(&ri0p[bid * 8 + rl], packf(fmaxf(pa + c0own[rl], 0.f), tag));
  };
  produce(1u);  // ri0 for step 0

  float v_reg = 0.f;
  for (int t = 0; t < steps; ++t) {
    const unsigned tg = (unsigned)(t + 1);

    // ==== Phase A: wait ri0 -> i1 -> LSTM -> LN -> qn -> sweep -> partials ====
    {
      ull u; int guard = 0;
      for (;;) {
        u = ld_pair(&ri0p[tid]);
        if (ptag(u) == tg) break;
        if (++guard > (1 << 16)) break;  // failsafe: never hang
        __builtin_amdgcn_s_sleep(1);
      }
      ri0_s[(tid >> 5) * 33 + (tid & 31)] = pvalf(u);
    }
    __syncthreads();
    const int act = (done_s == 0);
    {  // i1 = relu(W_a1 @ ri0 + b_a1)
      const int r = tid >> 3, s8 = tid & 7;
      float p1 = 0.f;
      #pragma unroll
      for (int i = 0; i < 8; ++i) {
        const float* xx = &ri0_s[s8 * 33 + 4 * i];
        p1 += w1[i].x * xx[0] + w1[i].y * xx[1] + w1[i].z * xx[2] + w1[i].w * xx[3];
      }
      #pragma unroll
      for (int m = 4; m; m >>= 1) p1 += __shfl_xor(p1, m);
      if (s8 == 0) x_i1[r] = fmaxf(p1 + b_a1s[r], 0.f);
    }
    __syncthreads();
    {  // 4 gate pre-activations
      const int rowg = tid >> 1, g = rowg >> 5, half = tid & 1;
      const float* xsrc = half ? q_s : x_i1;  // x = concat(i1, q)
      float pg = 0.f;
      #pragma unroll
      for (int i = 0; i < 8; ++i)
        pg += wg[i].x * xsrc[4 * i] + wg[i].y * xsrc[4 * i + 1] +
              wg[i].z * xsrc[4 * i + 2] + wg[i].w * xsrc[4 * i + 3];
      pg += __shfl_xor(pg, 1);
      if (!half) {
        pg += gb_s[rowg];
        garr[rowg] = (g == 2) ? tanhf(pg) : 1.f / (1.f + __expf(-pg));
      }
    }
    __syncthreads();
    {  // 3 layernorms in parallel (one per wave)
      const int w = tid >> 6, k = tid & 63;
      if (w < 3 && k < 32) {
        float a = (w == 0) ? garr[k] : (w == 1) ? garr[32 + k] * garr[64 + k] : garr[96 + k];
        float s = a;
        #pragma unroll
        for (int m = 16; m; m >>= 1) s += __shfl_xor(s, m);
        const float mean = s * (1.f / 32.f);
        const float d = a - mean;
        float vv = d * d;
        #pragma unroll
        for (int m = 16; m; m >>= 1) vv += __shfl_xor(vv, m);
        vv *= (1.f / 32.f);
        const float y = d * rsqrtf(vv + 1e-5f) * lng_s[k] + lnb_s[k];
        if (w == 0) fog[k] = y; else if (w == 1) rem[k] = y; else og[k] = y;
      }
    }
    __syncthreads();
    if (tid < 32) {
      const float nh = rem[tid] + fog[tid] * h_s[tid];
      const float qv = tanhf(nh) * og[tid];
      qnf[tid] = qv;                        // sweep always uses fresh qn
      if (act) { h_s[tid] = nh; q_s[tid] = qv; }
    }
    __syncthreads();
    {  // sweep over this block's 256 register-resident key columns
      float dot = 0.f;
      #pragma unroll
      for (int k = 0; k < 32; ++k) dot += qnf[k] * kc[k];
      const float sig = 1.f / (1.f + __expf(-dot));
      const float v = __expf(__logf(sig) / 0.8f);  // sig^(1/TEMP)
      v_reg = v;
      float sv = v, mv = v;
      int mi = (bid << 8) + tid;
      #pragma unroll
      for (int m = 32; m; m >>= 1) {
        sv += __shfl_xor(sv, m);
        const float ov = __shfl_xor(mv, m);
        const int oi = __shfl_xor(mi, m);
        if (ov > mv || (ov == mv && oi < mi)) { mv = ov; mi = oi; }
      }
      const int wv = tid >> 6;
      if ((tid & 63) == 0) { reds[wv] = sv; rmaxs[wv] = mv; ridxs[wv] = mi; }
    }
    __syncthreads();
    if (tid == 0) {
      float S = ((reds[0] + reds[1]) + reds[2]) + reds[3];
      float M = rmaxs[0]; int I = ridxs[0];
      #pragma unroll
      for (int i2 = 1; i2 < 4; ++i2)
        if (rmaxs[i2] > M || (rmaxs[i2] == M && ridxs[i2] < I)) { M = rmaxs[i2]; I = ridxs[i2]; }
      pickloc_s = I;
      ull* rec = &partp[bid * 40];
      st_pair(&rec[0], packf(S, tg));
      st_pair(&rec[1], packf(M, tg));
      st_pair(&rec[2], packi(I, tg));
    }
    __syncthreads();
    if ((bid << 8) + tid == pickloc_s) {  // local-argmax owner ships its column
      ull* rec = &partp[bid * 40];
      #pragma unroll
      for (int k = 0; k < 32; ++k) st_pair(&rec[3 + k], packf(kc[k], tg));
    }

    // ==== Phase B: wait partials -> redundant reduce/pick/ar update -> ri0(t+1) ====
    {
      const int b = tid >> 3, i = tid & 7;
      ull* rec = &partp[b * 40];
      ull u0, u1, u2, u3, u4 = 0;
      const bool f5 = (i < 3);  // items 32..34 exist only for i in {0,1,2}
      int guard = 0;
      for (;;) {
        u0 = ld_pair(&rec[i]);
        u1 = ld_pair(&rec[i + 8]);
        u2 = ld_pair(&rec[i + 16]);
        u3 = ld_pair(&rec[i + 24]);
        if (f5) u4 = ld_pair(&rec[i + 32]);
        bool ok = (ptag(u0) == tg) & (ptag(u1) == tg) & (ptag(u2) == tg) &
                  (ptag(u3) == tg) & (!f5 || (ptag(u4) == tg));
        if (ok) break;
        if (++guard > (1 << 16)) break;
        __builtin_amdgcn_s_sleep(1);
      }
      // stage: item 0 -> psum, 1 -> pmax, 2 -> pidx, 3..34 -> cand[item-3]
      ull us[5] = {u0, u1, u2, u3, u4};
      #pragma unroll
      for (int s5 = 0; s5 < 5; ++s5) {
        const int j = i + 8 * s5;
        if (j > 34) break;
        if (j == 0) psums[b] = pvalf(us[s5]);
        else if (j == 1) pmaxs[b] = pvalf(us[s5]);
        else if (j == 2) pidxs[b] = (int)(unsigned)us[s5];
        else cand_s[b * 32 + (j - 3)] = pvalf(us[s5]);
      }
    }
    __syncthreads();
    if (tid < 32) {  // redundant global reduce + centered selection
      float s = psums[tid], m = pmaxs[tid];
      int ii = pidxs[tid];
      #pragma unroll
      for (int mm = 16; mm; mm >>= 1) {
        s += __shfl_xor(s, mm);
        const float om = __shfl_xor(m, mm);
        const int oi = __shfl_xor(ii, mm);
        if (om > m || (om == m && oi < ii)) { m = om; ii = oi; }
      }
      const float kv = cand_s[(ii >> 8) * 32 + tid];  // keys[:, pick]
      float mn = kv;
      #pragma unroll
      for (int mm = 16; mm; mm >>= 1) mn += __shfl_xor(mn, mm);
      mn *= (1.f / 32.f);
      const float cv = kv - mn;
      cent[tid] = cv;
      const unsigned long long bb = __ballot(cv != cv);
      if (tid == 0) {
        const int valid = (s != 0.f);
        const int nf = (bb == 0) ? 1 : 0;
        const unsigned mw = maskb[ii >> 5];
        const int mv_ = (mw >> (ii & 31)) & 1;
        const int hit = (act && valid && mv_) ? 1 : 0;
        ssum_s = s;
        actvalid_s = (act && valid) ? 1 : 0;
        hit_s = hit;
        upd_s = (hit && nf) ? 1 : 0;
        if (hit) {
          maskb[ii >> 5] = mw & ~(1u << (ii & 31));
          selb[ii >> 5] |= (1u << (ii & 31));
          if (!nf) done_s = 1;
        }
      }
    }
    __syncthreads();
    {  // row write for step t (this block's 256 columns)
      const float rowv = actvalid_s ? (v_reg / ssum_s) : 0.f;
      __builtin_nontemporal_store(rowv, p.out + (size_t)t * N_ENT + (bid << 8) + tid);
    }
    if (upd_s) {  // ar += relu(W_a3 @ cent + b_a3), replicated full update
      #pragma unroll
      for (int rr = 0; rr < 4; ++rr) {
        const int r = tid + rr * 256;
        const float* wr = p.W_a3 + (size_t)r * KD;
        float dl = p.b_a3[r];
        #pragma unroll
        for (int c4 = 0; c4 < 8; ++c4) {
          v4f wv4 = *(const v4f*)(wr + 4 * c4);
          dl += wv4.x * cent[4 * c4] + wv4.y * cent[4 * c4 + 1] +
                wv4.z * cent[4 * c4 + 2] + wv4.w * cent[4 * c4 + 3];
        }
        if (dl > 0.f) ar_s[(r >> 5) * 36 + (r & 31)] += dl;
      }
    }
    __syncthreads();
    produce(tg + 1u);  // ri0 for step t+1
  }

  // ==== epilogue: sel_out and ar_out (replicated state, any block works) ====
  if (bid == 0) {
    for (int i = tid; i < N_ENT; i += 256)
      p.out[NN + i] = ((selb[i >> 5] >> (i & 31)) & 1u) ? 1.f : 0.f;
  } else if (bid == 1) {
    for (int i = tid; i < ARD; i += 256)
      p.out[NN + N_ENT + i] = ar_s[(i >> 5) * 36 + (i & 31)];
  }
}

extern "C" void kernel_launch(void* const* d_in, const int* in_sizes, int n_in,
                              void* d_out, int out_size, void* d_ws, size_t ws_size,
                              hipStream_t stream) {
  (void)in_sizes; (void)n_in; (void)out_size; (void)ws_size;
  Params p;
  p.um    = (const float*)d_in[0];
  p.emask = (const float*)d_in[1];
  p.enc   = (const float*)d_in[2];
  p.arin  = (const float*)d_in[3];
  p.W_fe  = (const float*)d_in[4];
  p.b_fe  = (const float*)d_in[5];
  p.W_k   = (const float*)d_in[6];
  p.b_k   = (const float*)d_in[7];
  p.W_a0  = (const float*)d_in[8];
  p.b_a0  = (const float*)d_in[9];
  p.W_a1  = (const float*)d_in[10];
  p.b_a1  = (const float*)d_in[11];
  p.W_f   = (const float*)d_in[12];
  p.b_f   = (const float*)d_in[13];
  p.W_i0  = (const float*)d_in[14];
  p.b_i0  = (const float*)d_in[15];
  p.W_i1  = (const float*)d_in[16];
  p.b_i1  = (const float*)d_in[17];
  p.W_o   = (const float*)d_in[18];
  p.b_o   = (const float*)d_in[19];
  p.ln_g  = (const float*)d_in[20];
  p.ln_b  = (const float*)d_in[21];
  p.W_a3  = (const float*)d_in[22];
  p.b_a3  = (const float*)d_in[23];
  p.ct    = (const int*)d_in[24];
  p.out   = (float*)d_out;
  p.wsf   = (float*)d_ws;
  p.wsi   = (int*)d_ws;

  hipLaunchKernelGGL(k_init, dim3(NBLK), dim3(256), 0, stream, p);
  hipLaunchKernelGGL(k_scan, dim3(NBLK), dim3(256), 0, stream, p);
}